// Round 4
// baseline (3617.435 us; speedup 1.0000x reference)
//
#include <hip/hip_runtime.h>
#include <hip/hip_bf16.h>

#define N_ENT 100000
#define HDIM 128
#define NE 200000
#define NR 460
#define NSTEP 4
#define SLOPE 0.22916666666666666f

__device__ __forceinline__ float sigm(float x) { return 1.0f / (1.0f + __expf(-x)); }

// ---------------------------------------------------------------------------
__global__ void zero_kernel(float* __restrict__ p, long n)
{
    long i = (long)blockIdx.x * 256 + threadIdx.x;
    if (i < n) p[i] = 0.0f;
}

__global__ void diag_kernel(float* o, float v)
{
    if (threadIdx.x == 0) o[0] = v;
}

// ---------------------------------------------------------------------------
// Prep: build transposes of Wx/Wh/gate_W/tdiff_W so GEMV inner loops read W
// coalesced (thread j = output index fast dim).  Copy rel state <- emb_rel.
// ---------------------------------------------------------------------------
__global__ void prep_kernel(
    const float* __restrict__ emb_rel,
    const float* __restrict__ Wx, const float* __restrict__ Wh,
    const float* __restrict__ Wg, const float* __restrict__ Wtd,
    float* __restrict__ rel,
    float* __restrict__ WxT, float* __restrict__ WhT,
    float* __restrict__ WgT, float* __restrict__ WtdT)
{
    int tid = blockIdx.x * blockDim.x + threadIdx.x;
    int nthr = gridDim.x * blockDim.x;
    for (int i = tid; i < NR * HDIM; i += nthr)
        rel[i] = emb_rel[i];
    for (int i = tid; i < 384 * 256; i += nthr) {   // Wx (384,256) -> WxT (256,384)
        int r = i >> 8, c = i & 255;
        WxT[c * 384 + r] = Wx[i];
    }
    for (int i = tid; i < 384 * 128; i += nthr) {   // Wh (384,128) -> WhT (128,384)
        int r = i >> 7, c = i & 127;
        WhT[c * 384 + r] = Wh[i];
    }
    for (int i = tid; i < 128 * 256; i += nthr) {   // Wg (128,256) -> WgT (256,128)
        int r = i >> 8, c = i & 255;
        WgT[c * 128 + r] = Wg[i];
    }
    for (int i = tid; i < 128 * 128; i += nthr) {   // Wtd (128,128) -> WtdT
        int r = i >> 7, c = i & 127;
        WtdT[c * 128 + r] = Wtd[i];
    }
}

// ---------------------------------------------------------------------------
// h0 = l2norm(dynamic_emb); one wave per row.
// ---------------------------------------------------------------------------
__global__ __launch_bounds__(64)
void norm_init_kernel(const float* __restrict__ emb, float* __restrict__ h)
{
    int row = blockIdx.x;
    int lane = threadIdx.x;
    float v0 = emb[row * HDIM + lane];
    float v1 = emb[row * HDIM + 64 + lane];
    float s = v0 * v0 + v1 * v1;
    #pragma unroll
    for (int off = 32; off; off >>= 1) s += __shfl_xor(s, off);
    float invn = 1.0f / fmaxf(sqrtf(s), 1e-12f);
    h[row * HDIM + lane] = v0 * invn;
    h[row * HDIM + 64 + lane] = v1 * invn;
}

// ---------------------------------------------------------------------------
// GRUCell relation evolution, in-place on rel (f32).  One block per relation.
// x = [emb_rel | rel_state] (2H), h = rel_state.
// ---------------------------------------------------------------------------
__global__ __launch_bounds__(128)
void gru_kernel(float* rel, const float* __restrict__ emb_rel,
                const float* __restrict__ WxT, const float* __restrict__ WhT,
                const float* __restrict__ bx, const float* __restrict__ bh)
{
    __shared__ __align__(16) float x[256];
    __shared__ __align__(16) float hh[128];
    int b = blockIdx.x, j = threadIdx.x;
    float hj = rel[b * HDIM + j];
    x[j] = emb_rel[b * HDIM + j];
    x[128 + j] = hj;
    hh[j] = hj;
    __syncthreads();
    float xr = 0, xz = 0, xn = 0, hr = 0, hz = 0, hn = 0;
    for (int k = 0; k < 256; k++) {
        float xv = x[k];
        const float* w = &WxT[k * 384];
        xr += xv * w[j];
        xz += xv * w[128 + j];
        xn += xv * w[256 + j];
    }
    for (int k = 0; k < 128; k++) {
        float hv = hh[k];
        const float* w = &WhT[k * 384];
        hr += hv * w[j];
        hz += hv * w[128 + j];
        hn += hv * w[256 + j];
    }
    float r = sigm(xr + bx[j] + hr + bh[j]);
    float z = sigm(xz + bx[128 + j] + hz + bh[128 + j]);
    float n = tanhf(xn + bx[256 + j] + r * (hn + bh[256 + j]));
    rel[b * HDIM + j] = (1.0f - z) * n + z * hj;
}

// ---------------------------------------------------------------------------
// Edge scatter for dst-chunk [lo,hi): agg[(dst-lo)] += hin[src] + rel[etype].
// 2 edges per 256-thread block; chunk test is wave-uniform.
// ---------------------------------------------------------------------------
__global__ __launch_bounds__(256)
void scatter_kernel(const int* __restrict__ src, const int* __restrict__ dst,
                    const int* __restrict__ et,
                    const float* __restrict__ hin, const float* __restrict__ rel,
                    float* __restrict__ agg, float* __restrict__ deg,
                    int lo, int hi, int do_deg)
{
    int idx = blockIdx.x * 256 + threadIdx.x;
    int e = idx >> 7;
    int i = idx & 127;
    int d = dst[e];
    if (d < lo || d >= hi) return;
    int s = src[e], r = et[e];
    float v = hin[s * HDIM + i] + rel[r * HDIM + i];
    atomicAdd(&agg[(d - lo) * HDIM + i], v);
    if (do_deg && i == 0) atomicAdd(&deg[d], 1.0f);
}

// ---------------------------------------------------------------------------
// Layer GEMM over chunk rows: out = rrelu((agg/max(deg,1)) @ Wn + hin @ Wl).
// 16 rows per block.  Self-zeroes consumed agg (and deg rows if zero_deg).
// hin and out are DIFFERENT buffers (no aliasing even when chunked).
// ---------------------------------------------------------------------------
__global__ __launch_bounds__(256)
void layer_kernel(float* agg, const float* __restrict__ hin, float* deg,
                  const float* __restrict__ Wn, const float* __restrict__ Wl,
                  float* __restrict__ out, int lo, int zero_deg)
{
    __shared__ __align__(16) float xs[16][HDIM];
    __shared__ __align__(16) float hs[16][HDIM];
    int lrow0 = blockIdx.x * 16;       // chunk-local row base
    int grow0 = lo + lrow0;            // global row base
    int tid = threadIdx.x;

    #pragma unroll
    for (int it = 0; it < 2; it++) {
        int e4 = it * 256 + tid;       // 0..511 float4 slots
        int r = e4 >> 5;
        int c = (e4 & 31) * 4;
        float rdeg = 1.0f / fmaxf(deg[grow0 + r], 1.0f);
        const float4 a = *(const float4*)&agg[(lrow0 + r) * HDIM + c];
        const float4 hv = *(const float4*)&hin[(grow0 + r) * HDIM + c];
        xs[r][c + 0] = a.x * rdeg;
        xs[r][c + 1] = a.y * rdeg;
        xs[r][c + 2] = a.z * rdeg;
        xs[r][c + 3] = a.w * rdeg;
        hs[r][c + 0] = hv.x;
        hs[r][c + 1] = hv.y;
        hs[r][c + 2] = hv.z;
        hs[r][c + 3] = hv.w;
        *(float4*)&agg[(lrow0 + r) * HDIM + c] = make_float4(0.f, 0.f, 0.f, 0.f);
    }
    __syncthreads();
    if (zero_deg && tid < 16) deg[grow0 + tid] = 0.0f;

    int j = tid & 127, rg = tid >> 7;
    float acc[8];
    #pragma unroll
    for (int r = 0; r < 8; r++) acc[r] = 0.0f;

    for (int k = 0; k < HDIM; k += 4) {
        float w0 = Wn[(k + 0) * HDIM + j];
        float w1 = Wn[(k + 1) * HDIM + j];
        float w2 = Wn[(k + 2) * HDIM + j];
        float w3 = Wn[(k + 3) * HDIM + j];
        #pragma unroll
        for (int r = 0; r < 8; r++) {
            float4 x4 = *(const float4*)&xs[rg * 8 + r][k];
            acc[r] += x4.x * w0 + x4.y * w1 + x4.z * w2 + x4.w * w3;
        }
    }
    for (int k = 0; k < HDIM; k += 4) {
        float w0 = Wl[(k + 0) * HDIM + j];
        float w1 = Wl[(k + 1) * HDIM + j];
        float w2 = Wl[(k + 2) * HDIM + j];
        float w3 = Wl[(k + 3) * HDIM + j];
        #pragma unroll
        for (int r = 0; r < 8; r++) {
            float4 h4 = *(const float4*)&hs[rg * 8 + r][k];
            acc[r] += h4.x * w0 + h4.y * w1 + h4.z * w2 + h4.w * w3;
        }
    }
    #pragma unroll
    for (int r = 0; r < 8; r++) {
        float v = acc[r];
        v = v >= 0.0f ? v : SLOPE * v;
        out[(grow0 + rg * 8 + r) * HDIM + j] = v;
    }
}

// ---------------------------------------------------------------------------
// Epilogue: l2norm(cur); time-gate; GatedFusion; TemporalDiffFusion.
// 16 rows/block; outp may alias cur or hprev (rows staged to LDS first,
// blocks touch disjoint rows).
// ---------------------------------------------------------------------------
__global__ __launch_bounds__(256)
void epilogue_kernel(const float* cur, const float* hprev,
                     const float* __restrict__ Wt, const float* __restrict__ bt,
                     const float* __restrict__ WgT, const float* __restrict__ bg,
                     const float* __restrict__ WtdT, const float* __restrict__ btd,
                     float* outp)
{
    __shared__ __align__(16) float cs[16][HDIM];
    __shared__ __align__(16) float hsh[16][HDIM];
    __shared__ __align__(16) float h1s[16][HDIM];
    __shared__ float invn[16];
    int row0 = blockIdx.x * 16;
    int tid = threadIdx.x;

    #pragma unroll
    for (int it = 0; it < 2; it++) {
        int e4 = it * 256 + tid;
        int r = e4 >> 5;
        int c = (e4 & 31) * 4;
        *(float4*)&cs[r][c]  = *(const float4*)&cur[(row0 + r) * HDIM + c];
        *(float4*)&hsh[r][c] = *(const float4*)&hprev[(row0 + r) * HDIM + c];
    }
    __syncthreads();

    int wv = tid >> 6, lane = tid & 63;
    #pragma unroll
    for (int q = 0; q < 4; q++) {
        int r = wv * 4 + q;
        float a = cs[r][lane], b = cs[r][lane + 64];
        float s = a * a + b * b;
        #pragma unroll
        for (int off = 32; off; off >>= 1) s += __shfl_xor(s, off);
        if (lane == 0) invn[r] = 1.0f / fmaxf(sqrtf(s), 1e-12f);
    }
    __syncthreads();

    int j = tid & 127, rg = tid >> 7;
    float cn[8], hv[8];
    #pragma unroll
    for (int r = 0; r < 8; r++) {
        int R = rg * 8 + r;
        float c = cs[R][j] * invn[R];
        cn[r] = c;
        cs[R][j] = c;           // normalized cur back to LDS
        hv[r] = hsh[R][j];
    }
    __syncthreads();

    // time gate: tw = sigmoid(cur_n @ Wt + bt);  h1 = tw*cur_n + (1-tw)*h
    float acc[8];
    #pragma unroll
    for (int r = 0; r < 8; r++) acc[r] = 0.0f;
    for (int k = 0; k < HDIM; k += 4) {
        float w0 = Wt[(k + 0) * HDIM + j];
        float w1 = Wt[(k + 1) * HDIM + j];
        float w2 = Wt[(k + 2) * HDIM + j];
        float w3 = Wt[(k + 3) * HDIM + j];
        #pragma unroll
        for (int r = 0; r < 8; r++) {
            float4 c4 = *(const float4*)&cs[rg * 8 + r][k];
            acc[r] += c4.x * w0 + c4.y * w1 + c4.z * w2 + c4.w * w3;
        }
    }
    float h1r[8];
    #pragma unroll
    for (int r = 0; r < 8; r++) {
        int R = rg * 8 + r;
        float tw = sigm(acc[r] + bt[j]);
        float h1 = tw * cn[r] + (1.0f - tw) * hv[r];
        h1r[r] = h1;
        h1s[R][j] = h1;
    }
    __syncthreads();

    // gate = sigmoid([h1|h] @ gate_W.T + bg);  h2 = g*h1 + (1-g)*h
    #pragma unroll
    for (int r = 0; r < 8; r++) acc[r] = 0.0f;
    for (int k = 0; k < HDIM; k += 4) {
        float w0 = WgT[(k + 0) * HDIM + j];
        float w1 = WgT[(k + 1) * HDIM + j];
        float w2 = WgT[(k + 2) * HDIM + j];
        float w3 = WgT[(k + 3) * HDIM + j];
        #pragma unroll
        for (int r = 0; r < 8; r++) {
            float4 a4 = *(const float4*)&h1s[rg * 8 + r][k];
            acc[r] += a4.x * w0 + a4.y * w1 + a4.z * w2 + a4.w * w3;
        }
    }
    for (int k = 0; k < HDIM; k += 4) {
        float w0 = WgT[(128 + k + 0) * HDIM + j];
        float w1 = WgT[(128 + k + 1) * HDIM + j];
        float w2 = WgT[(128 + k + 2) * HDIM + j];
        float w3 = WgT[(128 + k + 3) * HDIM + j];
        #pragma unroll
        for (int r = 0; r < 8; r++) {
            float4 a4 = *(const float4*)&hsh[rg * 8 + r][k];
            acc[r] += a4.x * w0 + a4.y * w1 + a4.z * w2 + a4.w * w3;
        }
    }
    float h2r[8];
    #pragma unroll
    for (int r = 0; r < 8; r++) {
        int R = rg * 8 + r;
        float g = sigm(acc[r] + bg[j]);
        float h2 = g * h1r[r] + (1.0f - g) * hv[r];
        h2r[r] = h2;
        cs[R][j] = h2 - hv[r];  // d = h2 - h, reuse cs
    }
    __syncthreads();

    // out = h2 + relu(d @ tdiff_W.T + btd)
    #pragma unroll
    for (int r = 0; r < 8; r++) acc[r] = 0.0f;
    for (int k = 0; k < HDIM; k += 4) {
        float w0 = WtdT[(k + 0) * HDIM + j];
        float w1 = WtdT[(k + 1) * HDIM + j];
        float w2 = WtdT[(k + 2) * HDIM + j];
        float w3 = WtdT[(k + 3) * HDIM + j];
        #pragma unroll
        for (int r = 0; r < 8; r++) {
            float4 d4 = *(const float4*)&cs[rg * 8 + r][k];
            acc[r] += d4.x * w0 + d4.y * w1 + d4.z * w2 + d4.w * w3;
        }
    }
    #pragma unroll
    for (int r = 0; r < 8; r++) {
        int R = rg * 8 + r;
        float td = fmaxf(acc[r] + btd[j], 0.0f);
        outp[(row0 + R) * HDIM + j] = h2r[r] + td;
    }
}

// ---------------------------------------------------------------------------
extern "C" void kernel_launch(void* const* d_in, const int* in_sizes, int n_in,
                              void* d_out, int out_size, void* d_ws, size_t ws_size,
                              hipStream_t stream)
{
    const int* src = (const int*)d_in[0];
    const int* dst = (const int*)d_in[1];
    const int* ety = (const int*)d_in[2];
    const float* dyn     = (const float*)d_in[3];
    const float* emb_rel = (const float*)d_in[4];
    const float* Wn1     = (const float*)d_in[5];
    const float* Wl1     = (const float*)d_in[6];
    const float* Wn2     = (const float*)d_in[7];
    const float* Wl2     = (const float*)d_in[8];
    const float* gWx     = (const float*)d_in[9];
    const float* gWh     = (const float*)d_in[10];
    const float* gbx     = (const float*)d_in[11];
    const float* gbh     = (const float*)d_in[12];
    const float* gateW   = (const float*)d_in[13];
    const float* gateb   = (const float*)d_in[14];
    const float* tdW     = (const float*)d_in[15];
    const float* tdb     = (const float*)d_in[16];
    const float* tgW     = (const float*)d_in[17];
    const float* tgb     = (const float*)d_in[18];

    const long NH = (long)N_ENT * HDIM;          // 12,800,000
    float* ws = (float*)d_ws;
    long off = 0;
    float* A    = ws + off; off += NH;           // h state
    float* B    = ws + off; off += NH;           // layer-1 output
    float* rel  = ws + off; off += (long)NR * HDIM;
    float* WxT  = ws + off; off += 98304;
    float* WhT  = ws + off; off += 49152;
    float* WgT  = ws + off; off += 32768;
    float* WtdT = ws + off; off += 16384;
    float* deg  = ws + off; off += 100352;       // N_ENT padded
    float* agg  = ws + off;                      // chunk*128 floats
    float* C    = (float*)d_out;                 // layer-2 output (NH f32)

    // Largest dst-chunk (fewest passes) whose agg fits; multiples of 16.
    const long avail = (long)(ws_size / 4) - off;
    const int cand[5] = {100000, 50000, 25008, 12512, 6256};
    int chunk = -1;
    for (int c = 0; c < 5; c++)
        if (avail >= (long)cand[c] * HDIM) { chunk = cand[c]; break; }

    if (chunk < 0) {                             // ws too small: report size
        diag_kernel<<<1, 64, 0, stream>>>((float*)d_out, (float)ws_size);
        return;
    }

    {   // zero deg + agg (contiguous)
        long nz = 100352 + (long)chunk * HDIM;
        zero_kernel<<<(int)((nz + 255) / 256), 256, 0, stream>>>(deg, nz);
    }

    prep_kernel<<<256, 256, 0, stream>>>(emb_rel, gWx, gWh, gateW, tdW,
                                         rel, WxT, WhT, WgT, WtdT);

    norm_init_kernel<<<N_ENT, 64, 0, stream>>>(dyn, A);

    const int scatter_grid = NE * HDIM / 256;    // 100000 blocks
    const int epi_grid = N_ENT / 16;             // 6250 blocks

    for (int t = 0; t < NSTEP; t++) {
        const int* st = src + (long)t * NE;
        const int* dt = dst + (long)t * NE;
        const int* et = ety + (long)t * NE;

        gru_kernel<<<NR, 128, 0, stream>>>(rel, emb_rel, WxT, WhT, gbx, gbh);

        // layer 1: A -> B (chunked over dst rows)
        for (int lo = 0; lo < N_ENT; lo += chunk) {
            int hi = lo + chunk > N_ENT ? N_ENT : lo + chunk;
            scatter_kernel<<<scatter_grid, 256, 0, stream>>>(
                st, dt, et, A, rel, agg, deg, lo, hi, 1);
            layer_kernel<<<(hi - lo) / 16, 256, 0, stream>>>(
                agg, A, deg, Wn1, Wl1, B, lo, 0);
        }
        // layer 2: B -> C
        for (int lo = 0; lo < N_ENT; lo += chunk) {
            int hi = lo + chunk > N_ENT ? N_ENT : lo + chunk;
            scatter_kernel<<<scatter_grid, 256, 0, stream>>>(
                st, dt, et, B, rel, agg, deg, lo, hi, 0);
            layer_kernel<<<(hi - lo) / 16, 256, 0, stream>>>(
                agg, B, deg, Wn2, Wl2, C, lo, 1);
        }

        // epilogue: (C, A) -> A   (t<3)  or  -> d_out == C  (t=3)
        float* outp = (t == NSTEP - 1) ? C : A;
        epilogue_kernel<<<epi_grid, 256, 0, stream>>>(
            C, A, tgW, tgb, WgT, gateb, WtdT, tdb, outp);
    }
}

// Round 5
// 1905.724 us; speedup vs baseline: 1.8982x; 1.8982x over previous
//
#include <hip/hip_runtime.h>
#include <hip/hip_bf16.h>

#define N_ENT 100000
#define HDIM 128
#define NE 200000
#define NR 460
#define NSTEP 4
#define SLOPE 0.22916666666666666f

typedef __attribute__((ext_vector_type(8))) short short8;
typedef __attribute__((ext_vector_type(4))) float f32x4;

__device__ __forceinline__ float sigm(float x) { return 1.0f / (1.0f + __expf(-x)); }
__device__ __forceinline__ short f2bs(float f) {
    __hip_bfloat16 b = __float2bfloat16(f);
    short s; __builtin_memcpy(&s, &b, 2); return s;
}

// ---------------------------------------------------------------------------
__global__ void zero_kernel(float* __restrict__ p, long n)
{
    long i = (long)blockIdx.x * 256 + threadIdx.x;
    if (i < n) p[i] = 0.0f;
}

__global__ void diag_kernel(float* o, float v)
{
    if (threadIdx.x == 0) o[0] = v;
}

// ---------------------------------------------------------------------------
// Prep: GRU weight transposes (f32) + bf16 B^T-layout buffers for the 5 MFMA
// GEMMs.  BT[n][k] so that C[row,n] = sum_k A[row,k]*BT[n][k].
// ---------------------------------------------------------------------------
__global__ void prep_kernel(
    const float* __restrict__ emb_rel,
    const float* __restrict__ Wx, const float* __restrict__ Wh,
    const float* __restrict__ Wn1, const float* __restrict__ Wl1,
    const float* __restrict__ Wn2, const float* __restrict__ Wl2,
    const float* __restrict__ tgW, const float* __restrict__ gateW,
    const float* __restrict__ tdW,
    float* __restrict__ rel,
    float* __restrict__ WxT, float* __restrict__ WhT,
    short* __restrict__ BT1, short* __restrict__ BT2,
    short* __restrict__ BTe1, short* __restrict__ BTe2,
    short* __restrict__ BTe3)
{
    int tid = blockIdx.x * blockDim.x + threadIdx.x;
    int nthr = gridDim.x * blockDim.x;
    for (int i = tid; i < NR * HDIM; i += nthr)
        rel[i] = emb_rel[i];
    for (int i = tid; i < 384 * 256; i += nthr) {   // Wx (384,256) -> WxT
        int r = i >> 8, c = i & 255;
        WxT[c * 384 + r] = Wx[i];
    }
    for (int i = tid; i < 384 * 128; i += nthr) {   // Wh (384,128) -> WhT
        int r = i >> 7, c = i & 127;
        WhT[c * 384 + r] = Wh[i];
    }
    for (int i = tid; i < 128 * 256; i += nthr) {   // layer BTs: [x|h]@[Wn;Wl]
        int n = i >> 8, k = i & 255;
        float v1 = (k < 128) ? Wn1[k * 128 + n] : Wl1[(k - 128) * 128 + n];
        float v2 = (k < 128) ? Wn2[k * 128 + n] : Wl2[(k - 128) * 128 + n];
        BT1[n * 256 + k] = f2bs(v1);
        BT2[n * 256 + k] = f2bs(v2);
    }
    for (int i = tid; i < 128 * 128; i += nthr) {   // E1: cur_n @ tgW (transpose)
        int n = i >> 7, k = i & 127;                 // E3: d @ tdW.T (direct)
        BTe1[n * 128 + k] = f2bs(tgW[k * 128 + n]);
        BTe3[n * 128 + k] = f2bs(tdW[n * 128 + k]);
    }
    for (int i = tid; i < 128 * 256; i += nthr) {   // E2: [h1|h] @ gateW.T (direct)
        int n = i >> 8, k = i & 255;
        BTe2[n * 256 + k] = f2bs(gateW[n * 256 + k]);
    }
}

// ---------------------------------------------------------------------------
// h0 = l2norm(dynamic_emb); one wave per row.
// ---------------------------------------------------------------------------
__global__ __launch_bounds__(64)
void norm_init_kernel(const float* __restrict__ emb, float* __restrict__ h)
{
    int row = blockIdx.x, lane = threadIdx.x;
    float v0 = emb[row * HDIM + lane];
    float v1 = emb[row * HDIM + 64 + lane];
    float s = v0 * v0 + v1 * v1;
    #pragma unroll
    for (int off = 32; off; off >>= 1) s += __shfl_xor(s, off);
    float invn = 1.0f / fmaxf(sqrtf(s), 1e-12f);
    h[row * HDIM + lane] = v0 * invn;
    h[row * HDIM + 64 + lane] = v1 * invn;
}

// row inverse-norms only (for E1's scaled A-operand)
__global__ __launch_bounds__(64)
void rownorm_kernel(const float* __restrict__ x, float* __restrict__ invn)
{
    int row = blockIdx.x, lane = threadIdx.x;
    float a = x[row * HDIM + lane];
    float b = x[row * HDIM + 64 + lane];
    float s = a * a + b * b;
    #pragma unroll
    for (int off = 32; off; off >>= 1) s += __shfl_xor(s, off);
    if (lane == 0) invn[row] = 1.0f / fmaxf(sqrtf(s), 1e-12f);
}

// ---------------------------------------------------------------------------
// GRUCell relation evolution (f32 GEMV — tiny: 460 rows).
// ---------------------------------------------------------------------------
__global__ __launch_bounds__(128)
void gru_kernel(float* rel, const float* __restrict__ emb_rel,
                const float* __restrict__ WxT, const float* __restrict__ WhT,
                const float* __restrict__ bx, const float* __restrict__ bh)
{
    __shared__ __align__(16) float x[256];
    __shared__ __align__(16) float hh[128];
    int b = blockIdx.x, j = threadIdx.x;
    float hj = rel[b * HDIM + j];
    x[j] = emb_rel[b * HDIM + j];
    x[128 + j] = hj;
    hh[j] = hj;
    __syncthreads();
    float xr = 0, xz = 0, xn = 0, hr = 0, hz = 0, hn = 0;
    for (int k = 0; k < 256; k++) {
        float xv = x[k];
        const float* w = &WxT[k * 384];
        xr += xv * w[j]; xz += xv * w[128 + j]; xn += xv * w[256 + j];
    }
    for (int k = 0; k < 128; k++) {
        float hv = hh[k];
        const float* w = &WhT[k * 384];
        hr += hv * w[j]; hz += hv * w[128 + j]; hn += hv * w[256 + j];
    }
    float r = sigm(xr + bx[j] + hr + bh[j]);
    float z = sigm(xz + bx[128 + j] + hz + bh[128 + j]);
    float n = tanhf(xn + bx[256 + j] + r * (hn + bh[256 + j]));
    rel[b * HDIM + j] = (1.0f - z) * n + z * hj;
}

// ---------------------------------------------------------------------------
// Edge scatter for dst-chunk [lo,hi): agg[(dst-lo)] += hin[src] + rel[etype].
// ---------------------------------------------------------------------------
__global__ __launch_bounds__(256)
void scatter_kernel(const int* __restrict__ src, const int* __restrict__ dst,
                    const int* __restrict__ et,
                    const float* __restrict__ hin, const float* __restrict__ rel,
                    float* __restrict__ agg, float* __restrict__ deg,
                    int lo, int hi, int do_deg)
{
    int idx = blockIdx.x * 256 + threadIdx.x;
    int e = idx >> 7;
    int i = idx & 127;
    int d = dst[e];
    if (d < lo || d >= hi) return;
    int s = src[e], r = et[e];
    float v = hin[s * HDIM + i] + rel[r * HDIM + i];
    atomicAdd(&agg[(long)(d - lo) * HDIM + i], v);
    if (do_deg && i == 0) atomicAdd(&deg[d], 1.0f);
}

// ---------------------------------------------------------------------------
// Generic MFMA GEMM: C[M x 128] = A[M x KT] @ BT^T, bf16 inputs, f32 acc.
// Block: 256 thr = 4 waves; wave owns 64 rows x 128 cols (4 row-tiles x 8
// col-tiles of 16x16x32 MFMA).  BT staged in LDS (pad 8 -> 2-way only).
// A streamed from global f32 -> bf16 frags (per-wave-private rows, so all
// in-place output aliasing below is race-free).
// MODE 0 layer: A=[agg*rdeg | h], epi rrelu, zero agg (+deg if zdeg)
// MODE 1 E1:    A=cur*invn,       epi tw=sig(c+b); h1=tw*curn+(1-tw)*h
// MODE 2 E2:    A=[h1 | h],       epi g=sig(c+b);  h2=g*h1+(1-g)*h
// MODE 3 E3:    A=h2-h,           epi out=h2+relu(c+b)
// ---------------------------------------------------------------------------
template<int MODE, int KT>
__global__ __launch_bounds__(256, 2)
void gemm_kernel(const float* __restrict__ A1, const float* __restrict__ A2,
                 float* __restrict__ scl, const short* __restrict__ BTg,
                 const float* __restrict__ bias,
                 float* __restrict__ out0, float* __restrict__ x0,
                 const float* __restrict__ x1,
                 int lo, int hi, int zdeg)
{
    __shared__ short bt[128][KT + 8];
    const int tid = threadIdx.x;
    for (int i = tid * 8; i < 128 * KT; i += 256 * 8) {
        int n = i / KT, k = i % KT;
        *(short8*)&bt[n][k] = *(const short8*)&BTg[i];
    }
    __syncthreads();

    const int lane = tid & 63;
    const int wv = tid >> 6;
    const int m = lane & 15, q = lane >> 4;
    const int rowBase = lo + blockIdx.x * 256 + wv * 64;

    f32x4 acc[4][8];
    #pragma unroll
    for (int rt = 0; rt < 4; rt++)
        #pragma unroll
        for (int ct = 0; ct < 8; ct++)
            acc[rt][ct] = (f32x4)0.0f;

    float rs[4];
    #pragma unroll
    for (int rt = 0; rt < 4; rt++) {
        int row = rowBase + rt * 16 + m;
        if (MODE == 0)      rs[rt] = (row < hi) ? 1.0f / fmaxf(scl[row], 1.0f) : 0.0f;
        else if (MODE == 1) rs[rt] = (row < hi) ? scl[row] : 0.0f;
        else                rs[rt] = 1.0f;
    }

    for (int kc = 0; kc < KT / 32; kc++) {
        short8 a[4];
        #pragma unroll
        for (int rt = 0; rt < 4; rt++) {
            int row = rowBase + rt * 16 + m;
            float v[8];
            if (row < hi) {
                int k0 = kc * 32 + q * 8;
                const float* p;
                if (MODE == 0)
                    p = (kc < 4) ? &A1[(long)(row - lo) * HDIM + k0]
                                 : &A2[(long)row * HDIM + (k0 - 128)];
                else if (MODE == 2)
                    p = (kc < 4) ? &A1[(long)row * HDIM + k0]
                                 : &A2[(long)row * HDIM + (k0 - 128)];
                else
                    p = &A1[(long)row * HDIM + k0];
                float4 u0 = *(const float4*)p;
                float4 u1 = *(const float4*)(p + 4);
                v[0]=u0.x; v[1]=u0.y; v[2]=u0.z; v[3]=u0.w;
                v[4]=u1.x; v[5]=u1.y; v[6]=u1.z; v[7]=u1.w;
                if (MODE == 0) {
                    if (kc < 4) {
                        #pragma unroll
                        for (int i = 0; i < 8; i++) v[i] *= rs[rt];
                    }
                } else if (MODE == 1) {
                    #pragma unroll
                    for (int i = 0; i < 8; i++) v[i] *= rs[rt];
                } else if (MODE == 3) {
                    const float* p2 = &A2[(long)row * HDIM + k0];
                    float4 w0 = *(const float4*)p2;
                    float4 w1 = *(const float4*)(p2 + 4);
                    v[0]-=w0.x; v[1]-=w0.y; v[2]-=w0.z; v[3]-=w0.w;
                    v[4]-=w1.x; v[5]-=w1.y; v[6]-=w1.z; v[7]-=w1.w;
                }
            } else {
                #pragma unroll
                for (int i = 0; i < 8; i++) v[i] = 0.0f;
            }
            short8 t;
            #pragma unroll
            for (int i = 0; i < 8; i++) t[i] = f2bs(v[i]);
            a[rt] = t;
        }
        short8 b[8];
        #pragma unroll
        for (int ct = 0; ct < 8; ct++)
            b[ct] = *(const short8*)&bt[ct * 16 + m][kc * 32 + q * 8];
        #pragma unroll
        for (int rt = 0; rt < 4; rt++)
            #pragma unroll
            for (int ct = 0; ct < 8; ct++)
                acc[rt][ct] = __builtin_amdgcn_mfma_f32_16x16x32_bf16(
                    a[rt], b[ct], acc[rt][ct], 0, 0, 0);
    }

    // epilogue: C layout col = m, row-in-tile = q*4 + rg
    #pragma unroll
    for (int rt = 0; rt < 4; rt++) {
        #pragma unroll
        for (int rg = 0; rg < 4; rg++) {
            int row = rowBase + rt * 16 + q * 4 + rg;
            if (row >= hi) continue;
            #pragma unroll
            for (int ct = 0; ct < 8; ct++) {
                int col = ct * 16 + m;
                float c = acc[rt][ct][rg];
                long rc = (long)row * HDIM + col;
                if (MODE == 0) {
                    c = c >= 0.0f ? c : SLOPE * c;
                    out0[rc] = c;
                    x0[(long)(row - lo) * HDIM + col] = 0.0f;   // re-zero agg
                    if (zdeg && col == 0) scl[row] = 0.0f;      // re-zero deg
                } else if (MODE == 1) {
                    float tw = sigm(c + bias[col]);
                    float curn = x0[rc] * scl[row];
                    float hv = x1[rc];
                    out0[rc] = tw * curn + (1.0f - tw) * hv;
                } else if (MODE == 2) {
                    float g = sigm(c + bias[col]);
                    out0[rc] = g * x0[rc] + (1.0f - g) * x1[rc];
                } else {
                    float td = fmaxf(c + bias[col], 0.0f);
                    out0[rc] = x0[rc] + td;
                }
            }
        }
    }
}

// ---------------------------------------------------------------------------
extern "C" void kernel_launch(void* const* d_in, const int* in_sizes, int n_in,
                              void* d_out, int out_size, void* d_ws, size_t ws_size,
                              hipStream_t stream)
{
    const int* src = (const int*)d_in[0];
    const int* dst = (const int*)d_in[1];
    const int* ety = (const int*)d_in[2];
    const float* dyn     = (const float*)d_in[3];
    const float* emb_rel = (const float*)d_in[4];
    const float* Wn1     = (const float*)d_in[5];
    const float* Wl1     = (const float*)d_in[6];
    const float* Wn2     = (const float*)d_in[7];
    const float* Wl2     = (const float*)d_in[8];
    const float* gWx     = (const float*)d_in[9];
    const float* gWh     = (const float*)d_in[10];
    const float* gbx     = (const float*)d_in[11];
    const float* gbh     = (const float*)d_in[12];
    const float* gateW   = (const float*)d_in[13];
    const float* gateb   = (const float*)d_in[14];
    const float* tdW     = (const float*)d_in[15];
    const float* tdb     = (const float*)d_in[16];
    const float* tgW     = (const float*)d_in[17];
    const float* tgb     = (const float*)d_in[18];

    const long NH = (long)N_ENT * HDIM;          // 12,800,000
    float* ws = (float*)d_ws;
    long off = 0;
    float* A    = ws + off; off += NH;           // h state
    float* B    = ws + off; off += NH;           // layer1 out -> h1 -> h2
    float* rel  = ws + off; off += (long)NR * HDIM;
    float* WxT  = ws + off; off += 98304;
    float* WhT  = ws + off; off += 49152;
    float* invn = ws + off; off += 100352;
    short* BT1  = (short*)(ws + off); off += 16384;   // 128x256 bf16
    short* BT2  = (short*)(ws + off); off += 16384;
    short* BTe1 = (short*)(ws + off); off += 8192;    // 128x128 bf16
    short* BTe2 = (short*)(ws + off); off += 16384;
    short* BTe3 = (short*)(ws + off); off += 8192;
    float* deg  = ws + off; off += 100352;
    float* agg  = ws + off;                      // chunk*128 floats
    float* C    = (float*)d_out;                 // layer2 out (= cur)

    const long avail = (long)(ws_size / 4) - off;
    const int cand[5] = {100000, 50000, 25008, 12512, 6256};
    int chunk = -1;
    for (int c = 0; c < 5; c++)
        if (avail >= (long)cand[c] * HDIM) { chunk = cand[c]; break; }

    if (chunk < 0) {
        diag_kernel<<<1, 64, 0, stream>>>((float*)d_out, (float)ws_size);
        return;
    }

    {   // zero deg + agg (contiguous)
        long nz = 100352 + (long)chunk * HDIM;
        zero_kernel<<<(int)((nz + 255) / 256), 256, 0, stream>>>(deg, nz);
    }

    prep_kernel<<<256, 256, 0, stream>>>(
        emb_rel, gWx, gWh, Wn1, Wl1, Wn2, Wl2, tgW, gateW, tdW,
        rel, WxT, WhT, BT1, BT2, BTe1, BTe2, BTe3);

    norm_init_kernel<<<N_ENT, 64, 0, stream>>>(dyn, A);

    const int scatter_grid = NE * HDIM / 256;    // 100000 blocks
    const int e_grid = (N_ENT + 255) / 256;      // 391 blocks

    for (int t = 0; t < NSTEP; t++) {
        const int* st = src + (long)t * NE;
        const int* dt = dst + (long)t * NE;
        const int* et = ety + (long)t * NE;

        gru_kernel<<<NR, 128, 0, stream>>>(rel, emb_rel, WxT, WhT, gbx, gbh);

        // layer 1: A -> B
        for (int lo = 0; lo < N_ENT; lo += chunk) {
            int hi = lo + chunk > N_ENT ? N_ENT : lo + chunk;
            scatter_kernel<<<scatter_grid, 256, 0, stream>>>(
                st, dt, et, A, rel, agg, deg, lo, hi, 1);
            gemm_kernel<0, 256><<<(hi - lo + 255) / 256, 256, 0, stream>>>(
                agg, A, deg, BT1, nullptr, B, agg, nullptr, lo, hi, 0);
        }
        // layer 2: B -> C (re-zeroes deg for next step)
        for (int lo = 0; lo < N_ENT; lo += chunk) {
            int hi = lo + chunk > N_ENT ? N_ENT : lo + chunk;
            scatter_kernel<<<scatter_grid, 256, 0, stream>>>(
                st, dt, et, B, rel, agg, deg, lo, hi, 0);
            gemm_kernel<0, 256><<<(hi - lo + 255) / 256, 256, 0, stream>>>(
                agg, B, deg, BT2, nullptr, C, agg, nullptr, lo, hi, 1);
        }

        rownorm_kernel<<<N_ENT, 64, 0, stream>>>(C, invn);

        // E1: h1 = tw*cur_n + (1-tw)*h        (C,A) -> B
        gemm_kernel<1, 128><<<e_grid, 256, 0, stream>>>(
            C, nullptr, invn, BTe1, tgb, B, C, A, 0, N_ENT, 0);
        // E2: h2 = g*h1 + (1-g)*h             (B,A) -> B (in-place, per-wave rows)
        gemm_kernel<2, 256><<<e_grid, 256, 0, stream>>>(
            B, A, invn, BTe2, gateb, B, B, A, 0, N_ENT, 0);
        // E3: hnew = h2 + relu((h2-h)@WtdT+b) (B,A) -> A (t<3) or d_out (t=3)
        float* outp = (t == NSTEP - 1) ? C : A;
        gemm_kernel<3, 128><<<e_grid, 256, 0, stream>>>(
            B, A, invn, BTe3, tdb, outp, B, nullptr, 0, N_ENT, 0);
    }
}